// Round 21
// baseline (42.917 us; speedup 1.0000x reference)
//
#include <hip/hip_runtime.h>

// Locally-connected 2d: x[32,16,66,66], w[1,32,16,64,64,9], bias[1,32,64,64]
// out[32,32,64,64] fp32.
//
// R21 = R20 resubmitted verbatim (infra failure; never measured).
// R20: 2-tile software pipeline, 1 block/CU (T3/T4 counted-vmcnt pattern).
// R14/R18/R19 all ~39-40us with three different staging mechanisms => staging
// mechanics exonerated; co-resident blocks are PHASE-LOCKED (simultaneous
// drains, no overlap). Fix: one block per CU runs tiles t0,t1 as a pipeline:
//   issue af0,S0,af1,S1 (54 vmem, sched_barrier-pinned) ->
//   s_waitcnt vmcnt(27) + raw s_barrier -> T0 compute (S1 streams under it) ->
//   __syncthreads (vmcnt0: S1 already arrived) -> T1 compute.
// LDS 2x72KB fp32 (gload_lds direct, R19-verified formulas) = 144 KB ->
// 1 block/CU -> compiler occupancy heuristic allows full VGPR (no load-sink).
// Tiles: L0 = (d&7)*128 + (d>>3) (d<512), L1 = L0+64 -> bijective over 1024;
// h1 = h0+4, same wq. Per (h,w): GEMM 32x32x144, kflat=kappa*16+c, 9 MFMAs.

#define CI_ 16
#define H_  64
#define W_  64
#define XW_ 66

typedef float f32x16 __attribute__((ext_vector_type(16)));
typedef short s16x8  __attribute__((ext_vector_type(8)));

__device__ inline short f2bf(float f) {  // RNE float->bf16
  unsigned u = __builtin_bit_cast(unsigned, f);
  u += 0x7fffu + ((u >> 16) & 1u);
  return (short)(u >> 16);
}

__device__ inline void gload_lds16(const float* g, void* l) {
  __builtin_amdgcn_global_load_lds(
      (const __attribute__((address_space(1))) void*)g,
      (__attribute__((address_space(3))) void*)l, 16, 0, 0);
}

// ---- prep_x: x[b][c][hh][ww] f32 -> xP[hh][ww][b][c] bf16 (verified R8-R19) -
__global__ __launch_bounds__(256) void prep_x(const float* __restrict__ x,
                                              short* __restrict__ xP) {
  const int t = blockIdx.x * 256 + threadIdx.x;  // 66*66*32*2 = 278784 exact
  const int oct = t & 1;
  const int b   = (t >> 1) & 31;
  const int hhww = t >> 6;
  const float* sp = x + ((size_t)b * CI_ + oct * 8) * 4356 + hhww;
  s16x8 v;
#pragma unroll
  for (int e = 0; e < 8; ++e) v[e] = f2bf(sp[(size_t)e * 4356]);
  *(s16x8*)(xP + (size_t)t * 8) = v;
}

// ---- fused main: 512 blocks, 2 tiles each, pipelined ------------------------
__global__ __launch_bounds__(256) void lc2d_fused(
    const short* __restrict__ xP, const float* __restrict__ wt,
    const float* __restrict__ bias, float* __restrict__ out) {
  __shared__ float pw[2][18432];  // two 72-KB fp32 tile buffers = 144 KB

  const int d = blockIdx.x;                      // 0..511
  const int L0 = (d & 7) * 128 + (d >> 3);       // tile0; tile1 = L0 + 64
  const int wq = L0 & 15;
  const int h0 = L0 >> 4;
  const int h1 = h0 + 4;                         // (L0+64)>>4, same wq
  const int tx = threadIdx.x;                    // 0..63
  const int w2 = threadIdx.y;                    // 0..3 (wave id = w in quad)
  const int tid = w2 * 64 + tx;                  // 0..255
  const int ln   = tx & 31;                      // A-row (b) / B-col (o)
  const int half = tx >> 5;                      // c-half: c = half*8 + e
  const int w = wq * 4 + w2;

  const short* ap0 = xP + ln * 16 + half * 8;

  // ---- phase 1: issue ALL vmem (af0, S0, af1, S1), regions pinned ----------
  s16x8 af0[9], af1[9];
#pragma unroll
  for (int kk = 0; kk < 9; ++kk) {               // af0: 9 loads
    const int i = kk / 3, j = kk - 3 * i;
    af0[kk] = *(const s16x8*)(ap0 + (size_t)((h0 + i) * XW_ + (w + j)) * 512);
  }
  __builtin_amdgcn_sched_barrier(0);
#pragma unroll
  for (int i = 0; i < 18; ++i) {                 // S0: 18 gload_lds
    const int G = i * 256 + tid;
    const int segL = G / 9;
    const int q    = G - 9 * segL;
    const int o = segL & 31, c = segL >> 5;
    const float* src = wt +
        (((size_t)(o * 16 + c) * 9216 + (size_t)h0 * 144 + wq * 9 + q) << 2);
    gload_lds16(src, (char*)&pw[0][0] + (size_t)(i * 256 + w2 * 64) * 16);
  }
  __builtin_amdgcn_sched_barrier(0);
#pragma unroll
  for (int kk = 0; kk < 9; ++kk) {               // af1: 9 loads
    const int i = kk / 3, j = kk - 3 * i;
    af1[kk] = *(const s16x8*)(ap0 + (size_t)((h1 + i) * XW_ + (w + j)) * 512);
  }
  __builtin_amdgcn_sched_barrier(0);
#pragma unroll
  for (int i = 0; i < 18; ++i) {                 // S1: 18 gload_lds
    const int G = i * 256 + tid;
    const int segL = G / 9;
    const int q    = G - 9 * segL;
    const int o = segL & 31, c = segL >> 5;
    const float* src = wt +
        (((size_t)(o * 16 + c) * 9216 + (size_t)h1 * 144 + wq * 9 + q) << 2);
    gload_lds16(src, (char*)&pw[1][0] + (size_t)(i * 256 + w2 * 64) * 16);
  }
  __builtin_amdgcn_sched_barrier(0);

  // ---- phase 2: wait af0+S0 only (oldest 27); S1/af1 stay in flight --------
  asm volatile("s_waitcnt vmcnt(27)" ::: "memory");
  __builtin_amdgcn_sched_barrier(0);
  __builtin_amdgcn_s_barrier();                  // raw: no vmcnt(0) drain
  __builtin_amdgcn_sched_barrier(0);

  const int bbase = half * 9216 + ln * 36 + w2 * 9;  // dword idx in tile buf

  // ---- T0 compute (9 MFMAs) ------------------------------------------------
  f32x16 acc = {0,0,0,0,0,0,0,0,0,0,0,0,0,0,0,0};
#pragma unroll
  for (int kk = 0; kk < 9; ++kk) {
    s16x8 bf;
#pragma unroll
    for (int e = 0; e < 8; ++e) bf[e] = f2bf(pw[0][bbase + e * 1152 + kk]);
    acc = __builtin_amdgcn_mfma_f32_32x32x16_bf16(af0[kk], bf, acc, 0, 0, 0);
  }

  __syncthreads();  // vmcnt(0): S1+af1 drained (mostly arrived under T0)

  // ---- T0 epilogue (tr aliases pw[0]; reads done block-wide) ---------------
  float* tr = &pw[0][0];
#pragma unroll
  for (int r = 0; r < 16; ++r) {
    const int b = (r & 3) + 8 * (r >> 2) + 4 * half;
    tr[(w2 * 32 + b) * 32 + ln] = acc[r];
  }
  __syncthreads();
  {
    const int o = tid & 31;
    const int brow = tid >> 5;
    const float4 bv = *(const float4*)(bias + ((size_t)o * H_ + h0) * W_ + wq * 4);
#pragma unroll
    for (int it = 0; it < 4; ++it) {
      const int b = it * 8 + brow;
      float4 v;
      v.x = tr[(0 * 32 + b) * 32 + o] + bv.x;
      v.y = tr[(1 * 32 + b) * 32 + o] + bv.y;
      v.z = tr[(2 * 32 + b) * 32 + o] + bv.z;
      v.w = tr[(3 * 32 + b) * 32 + o] + bv.w;
      *(float4*)(out + ((size_t)b * 32 + o) * (H_ * W_) + h0 * W_ + wq * 4) = v;
    }
  }

  // ---- T1 compute (9 MFMAs, buf1 already resident) -------------------------
  f32x16 acc1 = {0,0,0,0,0,0,0,0,0,0,0,0,0,0,0,0};
#pragma unroll
  for (int kk = 0; kk < 9; ++kk) {
    s16x8 bf;
#pragma unroll
    for (int e = 0; e < 8; ++e) bf[e] = f2bf(pw[1][bbase + e * 1152 + kk]);
    acc1 = __builtin_amdgcn_mfma_f32_32x32x16_bf16(af1[kk], bf, acc1, 0, 0, 0);
  }

  __syncthreads();  // T0-epilogue tr reads done before tr reuse

  // ---- T1 epilogue ---------------------------------------------------------
#pragma unroll
  for (int r = 0; r < 16; ++r) {
    const int b = (r & 3) + 8 * (r >> 2) + 4 * half;
    tr[(w2 * 32 + b) * 32 + ln] = acc1[r];
  }
  __syncthreads();
  {
    const int o = tid & 31;
    const int brow = tid >> 5;
    const float4 bv = *(const float4*)(bias + ((size_t)o * H_ + h1) * W_ + wq * 4);
#pragma unroll
    for (int it = 0; it < 4; ++it) {
      const int b = it * 8 + brow;
      float4 v;
      v.x = tr[(0 * 32 + b) * 32 + o] + bv.x;
      v.y = tr[(1 * 32 + b) * 32 + o] + bv.y;
      v.z = tr[(2 * 32 + b) * 32 + o] + bv.z;
      v.w = tr[(3 * 32 + b) * 32 + o] + bv.w;
      *(float4*)(out + ((size_t)b * 32 + o) * (H_ * W_) + h1 * W_ + wq * 4) = v;
    }
  }
}

// ---- fallback (R7-verified, no workspace): gather MFMA ----------------------
__global__ __launch_bounds__(256, 4) void lc2d_mfma0(
    const float* __restrict__ xs, const float* __restrict__ wt,
    const float* __restrict__ bias, float* __restrict__ out) {
  __shared__ float wlds[8 * 32 * 36];
  const int d = blockIdx.x;
  const int L = (d & 7) * 128 + (d >> 3);
  const int wq = L & 15;
  const int h  = L >> 4;
  const int tx = threadIdx.x;
  const int w2 = threadIdx.y;
  const int ln = tx & 31;
  const int half = tx >> 5;
  const int tid = w2 * 64 + tx;
  const int w = wq * 4 + w2;
  f32x16 acc = {0,0,0,0,0,0,0,0,0,0,0,0,0,0,0,0};
  const int bbase = ln * 36 + w2 * 9;
  size_t abase = (size_t)ln * 69696 + (size_t)h * XW_ + w;

  for (int s = 0; s < 2; ++s) {
    const int c0 = s * 8;
    __syncthreads();
#pragma unroll
    for (int i = 0; i < 9; ++i) {
      const int f4 = tid + i * 256;
      const int cc = f4 / 288;
      const int rem = f4 - cc * 288;
      const int oo = rem / 9;
      const int q = rem - oo * 9;
      const float4* src = (const float4*)wt +
          (((size_t)oo * CI_ + (c0 + cc)) * H_ + h) * 144 + (size_t)wq * 9 + q;
      ((float4*)wlds)[f4] = *src;
    }
    __syncthreads();
#pragma unroll
    for (int cc = 0; cc < 8; ++cc) {
      const int c = c0 + cc;
      const float* ap = xs + abase + (size_t)c * 4356;
      float av[8] = {0,0,0,0,0,0,0,0};
      float bvv[8] = {0,0,0,0,0,0,0,0};
      av[0] = ap[half ? (2 * XW_ + 2) : 0];
      bvv[0] = wlds[cc * 1152 + bbase + (half ? 8 : 0)];
      if (half == 0) {
#pragma unroll
        for (int e = 1; e < 8; ++e) {
          const int i = e / 3, j = e - 3 * i;
          av[e] = ap[i * XW_ + j];
          bvv[e] = wlds[cc * 1152 + bbase + e];
        }
      }
      s16x8 afr, bfr;
#pragma unroll
      for (int e = 0; e < 8; ++e) { afr[e] = f2bf(av[e]); bfr[e] = f2bf(bvv[e]); }
      acc = __builtin_amdgcn_mfma_f32_32x32x16_bf16(afr, bfr, acc, 0, 0, 0);
    }
  }
  const float bvv = bias[((size_t)ln * H_ + h) * W_ + w];
#pragma unroll
  for (int r = 0; r < 16; ++r) {
    const int b = (r & 3) + 8 * (r >> 2) + 4 * half;
    out[(((size_t)b * 32 + ln) * H_ + h) * W_ + w] = acc[r] + bvv;
  }
}

extern "C" void kernel_launch(void* const* d_in, const int* in_sizes, int n_in,
                              void* d_out, int out_size, void* d_ws, size_t ws_size,
                              hipStream_t stream) {
  const float* x    = (const float*)d_in[0];
  const float* wt   = (const float*)d_in[1];
  const float* bias = (const float*)d_in[2];
  float* out = (float*)d_out;

  const size_t xp_bytes = (size_t)66 * 66 * 32 * 16 * sizeof(short);  // 4.46 MB
  if (ws_size >= xp_bytes) {
    short* xP = (short*)d_ws;
    prep_x<<<1089, 256, 0, stream>>>(x, xP);
    lc2d_fused<<<512, dim3(64, 4, 1), 0, stream>>>(xP, wt, bias, out);
  } else {
    lc2d_mfma0<<<1024, dim3(64, 4, 1), 0, stream>>>(x, wt, bias, out);
  }
}